// Round 2
// baseline (425.084 us; speedup 1.0000x reference)
//
#include <hip/hip_runtime.h>
#include <hip/hip_bf16.h>
#include <cstdint>
#include <cstddef>

// Problem dims (fixed by the reference)
#define T_STEPS 2048
#define BATCH   8
#define D_DIM   1024
#define M_ROWS  (T_STEPS * BATCH)   // 16384 rows of x
#define N_COLS  (2 * D_DIM)         // 2048: W_alpha rows ++ W_x rows
#define K_DIM   D_DIM               // 1024
#define NCH     (BATCH * D_DIM)     // 8192 independent recurrence channels

// GEMM tiling (m97 pattern: unpadded LDS, global_load_lds staging)
#define BM 128
#define BN 128
#define BK 32

typedef __bf16 bf16x8 __attribute__((ext_vector_type(8)));
typedef float  f32x4  __attribute__((ext_vector_type(4)));

__device__ __forceinline__ unsigned short f2bf_rne(float f) {
    union { float f; unsigned u; } c; c.f = f;
    unsigned u = c.u;
    u += 0x7fffu + ((u >> 16) & 1u);   // round-to-nearest-even (inputs finite)
    return (unsigned short)(u >> 16);
}

__device__ __forceinline__ float sigmoid_f(float z) {
    return 1.0f / (1.0f + __expf(-z));
}

// async global -> LDS DMA, 16 B per lane; LDS dest = wave-uniform base + lane*16
__device__ __forceinline__ void glds16(const void* gptr, void* lptr) {
    __builtin_amdgcn_global_load_lds(
        (const __attribute__((address_space(1))) unsigned int*)gptr,
        (__attribute__((address_space(3))) unsigned int*)lptr,
        16, 0, 0);
}

// ---------------------------------------------------------------------------
// fp32 -> bf16 convert (vectorized x4)
// ---------------------------------------------------------------------------
__global__ void cvt_bf16_kernel(const float* __restrict__ src,
                                unsigned short* __restrict__ dst, int n4) {
    int i = blockIdx.x * blockDim.x + threadIdx.x;
    if (i >= n4) return;
    float4 v = reinterpret_cast<const float4*>(src)[i];
    ushort4 o;
    o.x = f2bf_rne(v.x); o.y = f2bf_rne(v.y);
    o.z = f2bf_rne(v.z); o.w = f2bf_rne(v.w);
    reinterpret_cast<ushort4*>(dst)[i] = o;
}

// ---------------------------------------------------------------------------
// Fused bf16 MFMA GEMM (m97 structure): out[m,n] = sum_k x[m,k] * Wc[n,k]
//   n <  1024 -> alpha_out[m,n]   = sigmoid(acc + b_alpha[n])
//   n >= 1024 -> wx_out[m,n-1024] = acc + b[n-1024]
// 256 thr = 4 waves; tile 128x128, BK=32; wave = 64x64 (4x4 MFMA tiles).
// Staging via global_load_lds width=16: wave w, instr p stages 16-row segment
// seg = w*2+p: lane l -> global row seg*16 + l/4, cols (l&3)*8..+7;
// LDS dest = seg*512 shorts + l*8 shorts  ==> row-major [128][32] unpadded.
// ---------------------------------------------------------------------------
__global__ __launch_bounds__(256, 2)
void gemm_kernel(const unsigned short* __restrict__ A,   // [M][K] bf16 (x)
                 const unsigned short* __restrict__ Bm,  // [N][K] bf16 (W_alpha ++ W_x)
                 const float* __restrict__ b_alpha,      // [D]
                 const float* __restrict__ b_x,          // [D]
                 float* __restrict__ alpha_out,          // [M][D] fp32
                 float* __restrict__ wx_out)             // [M][D] fp32
{
    __shared__ unsigned short sA[BM * BK];   // 8 KB
    __shared__ unsigned short sB[BN * BK];   // 8 KB

    const int tid  = threadIdx.x;
    const int wave = tid >> 6;
    const int lane = tid & 63;
    const int rowBase = blockIdx.y * BM;
    const int colBase = blockIdx.x * BN;
    const int wr = (wave >> 1) * 64;
    const int wc = (wave & 1) * 64;

    const int laneHi = lane >> 4;           // 0..3
    const int laneLo = lane & 15;

    // DMA staging addresses (per lane): row sub-offset + col offset
    const int dRow = lane >> 2;             // 0..15
    const int dCol = (lane & 3) * 8;        // 0,8,16,24

    f32x4 acc[4][4];
#pragma unroll
    for (int i = 0; i < 4; i++)
#pragma unroll
        for (int j = 0; j < 4; j++)
            acc[i][j] = (f32x4)(0.0f);

    for (int k0 = 0; k0 < K_DIM; k0 += BK) {
#pragma unroll
        for (int p = 0; p < 2; ++p) {
            const int seg = wave * 2 + p;   // 16-row segment index, 0..7
            glds16(A + (size_t)(rowBase + seg * 16 + dRow) * K_DIM + k0 + dCol,
                   &sA[seg * 512]);
            glds16(Bm + (size_t)(colBase + seg * 16 + dRow) * K_DIM + k0 + dCol,
                   &sB[seg * 512]);
        }
        __syncthreads();   // compiler drains vmcnt(0) here -> LDS tiles ready

        bf16x8 af[4], bfr[4];
#pragma unroll
        for (int i = 0; i < 4; i++)
            af[i] = *reinterpret_cast<const bf16x8*>(
                &sA[(wr + i * 16 + laneLo) * BK + laneHi * 8]);
#pragma unroll
        for (int j = 0; j < 4; j++)
            bfr[j] = *reinterpret_cast<const bf16x8*>(
                &sB[(wc + j * 16 + laneLo) * BK + laneHi * 8]);
        __syncthreads();   // fragments in regs; LDS free for next k-step

#pragma unroll
        for (int i = 0; i < 4; i++)
#pragma unroll
            for (int j = 0; j < 4; j++)
                acc[i][j] = __builtin_amdgcn_mfma_f32_16x16x32_bf16(
                    af[i], bfr[j], acc[i][j], 0, 0, 0);
    }

    // Epilogue. C/D layout: col = lane&15, row = (lane>>4)*4 + reg  [m89/m91]
#pragma unroll
    for (int i = 0; i < 4; i++) {
        int row = rowBase + wr + i * 16 + laneHi * 4;
#pragma unroll
        for (int j = 0; j < 4; j++) {
            int col = colBase + wc + j * 16 + laneLo;
            if (col < D_DIM) {
                float bias = b_alpha[col];
#pragma unroll
                for (int r = 0; r < 4; r++) {
                    float z = acc[i][j][r] + bias;
                    alpha_out[(size_t)(row + r) * D_DIM + col] = sigmoid_f(z);
                }
            } else {
                int c2 = col - D_DIM;
                float bias = b_x[c2];
#pragma unroll
                for (int r = 0; r < 4; r++)
                    wx_out[(size_t)(row + r) * D_DIM + c2] = acc[i][j][r] + bias;
            }
        }
    }
}

// ---------------------------------------------------------------------------
// Sequential scan v3: barrier-free register-pipelined, 1 channel per lane.
//   128 blocks x 64 threads (1 wave, no LDS, no producer wave, no barriers).
//   Each lane owns channel ch = blockIdx*64 + lane and prefetches its own
//   (alpha, wx) DEPTH steps ahead into statically-indexed register rings;
//   the compiler emits COUNTED s_waitcnt vmcnt(N) per consumed register, so
//   loads stay in flight across steps (no vmcnt(0) drain anywhere).
//   48 outstanding VMEM ops/wave (2 loads + 1 store per step x DEPTH=16),
//   under the 63-slot HW limit. Loads are coalesced: 64 lanes x 4B = 256 B.
// Recurrence (5-op cross-step chain):
//   u = 1-a; p = C*h + C*w (C = 2*log2e); e = exp2(p); r = rcp(e+1);
//   m = a*h + u;  h' = m - 2u*r   [== a*h + (1-a)*tanh(h+w)]
// Prefetch over-reads up to DEPTH rows past t=T-1: lands in the adjacent
// workspace regions (ws_wx, then ws_x bf16) -- mapped, never consumed.
// ---------------------------------------------------------------------------
#define DEPTH 16

__global__ __launch_bounds__(64)
void scan_kernel(const float* __restrict__ alpha,  // [T][NCH] (+DEPTH overread ok)
                 const float* __restrict__ wx,     // [T][NCH] (+DEPTH overread ok)
                 const float* __restrict__ h0,     // [NCH]
                 float* __restrict__ hout)         // [T+1][NCH]
{
    const int lane = threadIdx.x;
    const int ch   = blockIdx.x * 64 + lane;

    const float C2L = 2.88539008177792681472f;   // 2*log2(e)

    const float* ap = alpha + ch;
    const float* wp = wx + ch;
    float* hp = hout + NCH + ch;

    float aP[DEPTH], wP[DEPTH];
#pragma unroll
    for (int d = 0; d < DEPTH; ++d) {
        aP[d] = ap[(size_t)d * NCH];
        wP[d] = wp[(size_t)d * NCH];
    }

    float h = h0[ch];
    hout[ch] = h;

    for (int t0 = 0; t0 < T_STEPS; t0 += DEPTH) {
#pragma unroll
        for (int d = 0; d < DEPTH; ++d) {
            const float a = aP[d];
            const float w = wP[d];
            // refill ring slot DEPTH steps ahead (counted-vmcnt consumed later)
            const size_t tn = (size_t)(t0 + DEPTH + d);
            aP[d] = ap[tn * NCH];
            wP[d] = wp[tn * NCH];
            // 5-op dependent chain
            const float u = 1.0f - a;
            const float p = fmaf(h, C2L, w * C2L);
            const float e = __builtin_amdgcn_exp2f(p);
            const float r = __builtin_amdgcn_rcpf(e + 1.0f);
            const float m = fmaf(a, h, u);
            h = fmaf(-(u + u), r, m);
            hp[(size_t)(t0 + d) * NCH] = h;
        }
    }
}

// ---------------------------------------------------------------------------
// out[t] = h_{t+1}^2 * sigmoid(h_{t+1})  == h*silu(h), fully parallel.
// Linear view: out[j] = f(hout[j + NCH]) for j in [0, T*NCH).
// ---------------------------------------------------------------------------
__global__ __launch_bounds__(256)
void out_kernel(const float* __restrict__ hnext,   // hout + NCH
                float* __restrict__ out, int n4) {
    const float L2E = 1.44269504088896340736f;
    int stride = gridDim.x * blockDim.x;
    for (int i = blockIdx.x * blockDim.x + threadIdx.x; i < n4; i += stride) {
        float4 h = reinterpret_cast<const float4*>(hnext)[i];
        float4 o;
        o.x = h.x * h.x * __builtin_amdgcn_rcpf(1.0f + __builtin_amdgcn_exp2f(-L2E * h.x));
        o.y = h.y * h.y * __builtin_amdgcn_rcpf(1.0f + __builtin_amdgcn_exp2f(-L2E * h.y));
        o.z = h.z * h.z * __builtin_amdgcn_rcpf(1.0f + __builtin_amdgcn_exp2f(-L2E * h.z));
        o.w = h.w * h.w * __builtin_amdgcn_rcpf(1.0f + __builtin_amdgcn_exp2f(-L2E * h.w));
        reinterpret_cast<float4*>(out)[i] = o;
    }
}

// ---------------------------------------------------------------------------
extern "C" void kernel_launch(void* const* d_in, const int* in_sizes, int n_in,
                              void* d_out, int out_size, void* d_ws, size_t ws_size,
                              hipStream_t stream) {
    const float* x       = (const float*)d_in[0];  // [T,B,D]
    const float* h0      = (const float*)d_in[1];  // [B,D]
    const float* W_alpha = (const float*)d_in[2];  // [D,D]
    const float* b_alpha = (const float*)d_in[3];  // [D]
    const float* W_x     = (const float*)d_in[4];  // [D,D]
    const float* b       = (const float*)d_in[5];  // [D]

    float* out  = (float*)d_out;                              // [T,B,D]
    float* hout = out + (size_t)T_STEPS * BATCH * D_DIM;      // [T+1,B,D]

    // Workspace layout (~164 MB):
    //   alpha fp32 (64 MB) | wx fp32 (64 MB) | x bf16 (32 MB) | Wc bf16 (4 MB)
    // NOTE: scan_kernel over-reads up to DEPTH rows past each region's end --
    // alpha overruns into wx, wx overruns into x (both mapped, never consumed).
    float* ws_alpha = (float*)d_ws;
    float* ws_wx    = ws_alpha + (size_t)M_ROWS * D_DIM;
    unsigned short* ws_x = (unsigned short*)(ws_wx + (size_t)M_ROWS * D_DIM);
    unsigned short* ws_W = ws_x + (size_t)M_ROWS * K_DIM;

    // 1) convert x, W_alpha, W_x to bf16
    {
        int n4 = M_ROWS * K_DIM / 4;
        cvt_bf16_kernel<<<(n4 + 255) / 256, 256, 0, stream>>>(x, ws_x, n4);
    }
    {
        int n4 = D_DIM * K_DIM / 4;
        cvt_bf16_kernel<<<(n4 + 255) / 256, 256, 0, stream>>>(W_alpha, ws_W, n4);
        cvt_bf16_kernel<<<(n4 + 255) / 256, 256, 0, stream>>>(
            W_x, ws_W + (size_t)D_DIM * K_DIM, n4);
    }

    // 2) fused GEMM (N = 2048 covers both projections) + bias + sigmoid epilogue
    {
        dim3 grid(N_COLS / BN, M_ROWS / BM);   // (16, 128)
        gemm_kernel<<<grid, 256, 0, stream>>>(ws_x, ws_W, b_alpha, b,
                                              ws_alpha, ws_wx);
    }

    // 3) sequential scan: 128 blocks x 1 wave, register-pipelined, barrier-free
    scan_kernel<<<NCH / 64, 64, 0, stream>>>(ws_alpha, ws_wx, h0, hout);

    // 4) out = h*silu(h), massively parallel from hout (shifted one row)
    {
        int n4 = (int)((size_t)T_STEPS * NCH / 4);
        out_kernel<<<2048, 256, 0, stream>>>(hout + NCH, out, n4);
    }
}

// Round 3
// 416.096 us; speedup vs baseline: 1.0216x; 1.0216x over previous
//
#include <hip/hip_runtime.h>
#include <hip/hip_bf16.h>
#include <cstdint>
#include <cstddef>

// Problem dims (fixed by the reference)
#define T_STEPS 2048
#define BATCH   8
#define D_DIM   1024
#define M_ROWS  (T_STEPS * BATCH)   // 16384 rows of x
#define N_COLS  (2 * D_DIM)         // 2048: W_alpha rows ++ W_x rows
#define K_DIM   D_DIM               // 1024
#define NCH     (BATCH * D_DIM)     // 8192 independent recurrence channels

// GEMM tiling (m97 pattern: unpadded LDS, global_load_lds staging)
#define BM 128
#define BN 128
#define BK 32

typedef __bf16 bf16x8 __attribute__((ext_vector_type(8)));
typedef float  f32x4  __attribute__((ext_vector_type(4)));

__device__ __forceinline__ unsigned short f2bf_rne(float f) {
    union { float f; unsigned u; } c; c.f = f;
    unsigned u = c.u;
    u += 0x7fffu + ((u >> 16) & 1u);   // round-to-nearest-even (inputs finite)
    return (unsigned short)(u >> 16);
}

__device__ __forceinline__ float sigmoid_f(float z) {
    return 1.0f / (1.0f + __expf(-z));
}

// async global -> LDS DMA, 16 B per lane; LDS dest = wave-uniform base + lane*16
__device__ __forceinline__ void glds16(const void* gptr, void* lptr) {
    __builtin_amdgcn_global_load_lds(
        (const __attribute__((address_space(1))) unsigned int*)gptr,
        (__attribute__((address_space(3))) unsigned int*)lptr,
        16, 0, 0);
}

// ---------------------------------------------------------------------------
// fp32 -> bf16 convert (vectorized x4)
// ---------------------------------------------------------------------------
__global__ void cvt_bf16_kernel(const float* __restrict__ src,
                                unsigned short* __restrict__ dst, int n4) {
    int i = blockIdx.x * blockDim.x + threadIdx.x;
    if (i >= n4) return;
    float4 v = reinterpret_cast<const float4*>(src)[i];
    ushort4 o;
    o.x = f2bf_rne(v.x); o.y = f2bf_rne(v.y);
    o.z = f2bf_rne(v.z); o.w = f2bf_rne(v.w);
    reinterpret_cast<ushort4*>(dst)[i] = o;
}

// ---------------------------------------------------------------------------
// Fused bf16 MFMA GEMM (m97 structure): out[m,n] = sum_k x[m,k] * Wc[n,k]
//   n <  1024 -> alpha_out[m,n]   = sigmoid(acc + b_alpha[n])
//   n >= 1024 -> wx_out[m,n-1024] = acc + b[n-1024]
// 256 thr = 4 waves; tile 128x128, BK=32; wave = 64x64 (4x4 MFMA tiles).
// XCD-bijective swizzle (T1): nwg=2048 (%8==0) -> each XCD gets 256
// consecutive tile indices = 16 full row-panels -> A-panel reuse is L2-local.
// ---------------------------------------------------------------------------
__global__ __launch_bounds__(256, 2)
void gemm_kernel(const unsigned short* __restrict__ A,   // [M][K] bf16 (x)
                 const unsigned short* __restrict__ Bm,  // [N][K] bf16 (W_alpha ++ W_x)
                 const float* __restrict__ b_alpha,      // [D]
                 const float* __restrict__ b_x,          // [D]
                 float* __restrict__ alpha_out,          // [M][D] fp32
                 float* __restrict__ wx_out)             // [M][D] fp32
{
    __shared__ unsigned short sA[BM * BK];   // 8 KB
    __shared__ unsigned short sB[BN * BK];   // 8 KB

    const int tid  = threadIdx.x;
    const int wave = tid >> 6;
    const int lane = tid & 63;

    // XCD swizzle: grid is (16, 128) = 2048 wgs; 2048 % 8 == 0 -> bijective
    const int orig = blockIdx.y * 16 + blockIdx.x;
    const int swz  = (orig & 7) * 256 + (orig >> 3);
    const int rowBase = (swz >> 4) * BM;
    const int colBase = (swz & 15) * BN;

    const int wr = (wave >> 1) * 64;
    const int wc = (wave & 1) * 64;

    const int laneHi = lane >> 4;           // 0..3
    const int laneLo = lane & 15;

    // DMA staging addresses (per lane): row sub-offset + col offset
    const int dRow = lane >> 2;             // 0..15
    const int dCol = (lane & 3) * 8;        // 0,8,16,24

    f32x4 acc[4][4];
#pragma unroll
    for (int i = 0; i < 4; i++)
#pragma unroll
        for (int j = 0; j < 4; j++)
            acc[i][j] = (f32x4)(0.0f);

    for (int k0 = 0; k0 < K_DIM; k0 += BK) {
#pragma unroll
        for (int p = 0; p < 2; ++p) {
            const int seg = wave * 2 + p;   // 16-row segment index, 0..7
            glds16(A + (size_t)(rowBase + seg * 16 + dRow) * K_DIM + k0 + dCol,
                   &sA[seg * 512]);
            glds16(Bm + (size_t)(colBase + seg * 16 + dRow) * K_DIM + k0 + dCol,
                   &sB[seg * 512]);
        }
        __syncthreads();   // compiler drains vmcnt(0) here -> LDS tiles ready

        bf16x8 af[4], bfr[4];
#pragma unroll
        for (int i = 0; i < 4; i++)
            af[i] = *reinterpret_cast<const bf16x8*>(
                &sA[(wr + i * 16 + laneLo) * BK + laneHi * 8]);
#pragma unroll
        for (int j = 0; j < 4; j++)
            bfr[j] = *reinterpret_cast<const bf16x8*>(
                &sB[(wc + j * 16 + laneLo) * BK + laneHi * 8]);
        __syncthreads();   // fragments in regs; LDS free for next k-step

#pragma unroll
        for (int i = 0; i < 4; i++)
#pragma unroll
            for (int j = 0; j < 4; j++)
                acc[i][j] = __builtin_amdgcn_mfma_f32_16x16x32_bf16(
                    af[i], bfr[j], acc[i][j], 0, 0, 0);
    }

    // Epilogue. C/D layout: col = lane&15, row = (lane>>4)*4 + reg  [m89/m91]
#pragma unroll
    for (int i = 0; i < 4; i++) {
        int row = rowBase + wr + i * 16 + laneHi * 4;
#pragma unroll
        for (int j = 0; j < 4; j++) {
            int col = colBase + wc + j * 16 + laneLo;
            if (col < D_DIM) {
                float bias = b_alpha[col];
#pragma unroll
                for (int r = 0; r < 4; r++) {
                    float z = acc[i][j][r] + bias;
                    alpha_out[(size_t)(row + r) * D_DIM + col] = sigmoid_f(z);
                }
            } else {
                int c2 = col - D_DIM;
                float bias = b_x[c2];
#pragma unroll
                for (int r = 0; r < 4; r++)
                    wx_out[(size_t)(row + r) * D_DIM + c2] = acc[i][j][r] + bias;
            }
        }
    }
}

// ---------------------------------------------------------------------------
// Sequential scan v4: SINGLE-WAVE double-buffered LDS with counted vmcnt.
//   128 blocks x 64 threads, 1 channel/lane. No barriers (one wave).
//   Per 32-step tile: issue 16 glds16 for tile t+1 into buf^1, then
//   s_waitcnt vmcnt(48) -- FIFO is [glds_t(16), stores(32), glds_{t+1}(16)],
//   so vmcnt(48) drains exactly glds_t while the t+1 prefetch stays in
//   flight (T4: never drain to 0 in the main loop). Prefetch latency hides
//   under ~1300 cycles of tile-t compute.
//   (Round-2 lesson: plain-load register rings get collapsed by the
//   compiler -- VGPR_Count=32 proved the ring never existed. global_load_lds
//   placement is the only source-level pin for prefetch distance.)
// Recurrence (5-op cross-step chain):
//   u = 1-a; p = C*h + C*w (C = 2*log2e); e = exp2(p); r = rcp(e+1);
//   m = a*h + u;  h' = m - 2u*r   [== a*h + (1-a)*tanh(h+w)]
// LDS tile buffer: row-major [TT][64] fp32; glds16 p stages timesteps
// 4p..4p+3 (lane l -> ts 4p + l/16, ch (l&15)*4). Stride-1 lane reads ->
// 2 lanes/bank = conflict-free.
// ---------------------------------------------------------------------------
#define TT 32
#define NT (T_STEPS / TT)   // 64 tiles

__device__ __forceinline__ float scan_tile_compute(const float* __restrict__ sA,
                                                   const float* __restrict__ sW,
                                                   float h, float* __restrict__ hp,
                                                   int tbase, int lane)
{
    const float C2L = 2.88539008177792681472f;   // 2*log2(e)
#pragma unroll 8
    for (int ts = 0; ts < TT; ++ts) {
        const float a = sA[ts * 64 + lane];
        const float w = sW[ts * 64 + lane];
        const float u = 1.0f - a;
        const float p = fmaf(h, C2L, w * C2L);
        const float e = __builtin_amdgcn_exp2f(p);
        const float r = __builtin_amdgcn_rcpf(e + 1.0f);
        const float m = fmaf(a, h, u);
        h = fmaf(-(u + u), r, m);
        hp[(size_t)(tbase + ts) * NCH] = h;
    }
    return h;
}

__global__ __launch_bounds__(64)
void scan_kernel(const float* __restrict__ alpha,  // [T][NCH]
                 const float* __restrict__ wx,     // [T][NCH]
                 const float* __restrict__ h0,     // [NCH]
                 float* __restrict__ hout)         // [T+1][NCH]
{
    __shared__ float sAl[2][TT * 64];   // 2 x 8 KB
    __shared__ float sWx[2][TT * 64];   // 2 x 8 KB

    const int lane = threadIdx.x;
    const int ch0  = blockIdx.x * 64;
    const int q    = lane >> 4;          // sub-timestep 0..3 within instr
    const int c4   = (lane & 15) * 4;    // channel group

    // stage tile 0 -> buf 0
#pragma unroll
    for (int p = 0; p < TT / 4; ++p) {
        const size_t g = (size_t)(p * 4 + q) * NCH + ch0 + c4;
        glds16(alpha + g, &sAl[0][p * 256]);
        glds16(wx    + g, &sWx[0][p * 256]);
    }

    float h = h0[ch0 + lane];
    hout[ch0 + lane] = h;
    float* hp = hout + NCH + ch0 + lane;

    // stage tile 1 -> buf 1 (2-deep prologue)
#pragma unroll
    for (int p = 0; p < TT / 4; ++p) {
        const size_t g = (size_t)(TT + p * 4 + q) * NCH + ch0 + c4;
        glds16(alpha + g, &sAl[1][p * 256]);
        glds16(wx    + g, &sWx[1][p * 256]);
    }

    // drain tile-0 glds only (tile-1's 16 stay in flight)
    asm volatile("s_waitcnt vmcnt(16)" ::: "memory");
    __builtin_amdgcn_sched_barrier(0);
    h = scan_tile_compute(&sAl[0][0], &sWx[0][0], h, hp, 0, lane);

    for (int tile = 1; tile < NT; ++tile) {
        const int cur = tile & 1;
        if (tile + 1 < NT) {
            const int t0n = (tile + 1) * TT;
#pragma unroll
            for (int p = 0; p < TT / 4; ++p) {
                const size_t g = (size_t)(t0n + p * 4 + q) * NCH + ch0 + c4;
                glds16(alpha + g, &sAl[cur ^ 1][p * 256]);
                glds16(wx    + g, &sWx[cur ^ 1][p * 256]);
            }
            // FIFO: glds_tile(16), stores_prev(32), glds_next(16)
            asm volatile("s_waitcnt vmcnt(48)" ::: "memory");
        } else {
            // last tile: FIFO = glds_tile(16), stores_prev(32)
            asm volatile("s_waitcnt vmcnt(32)" ::: "memory");
        }
        __builtin_amdgcn_sched_barrier(0);
        h = scan_tile_compute(&sAl[cur][0], &sWx[cur][0], h, hp, tile * TT, lane);
    }
}

// ---------------------------------------------------------------------------
// out[t] = h_{t+1}^2 * sigmoid(h_{t+1})  == h*silu(h), fully parallel.
// Linear view: out[j] = f(hout[j + NCH]) for j in [0, T*NCH).
// ---------------------------------------------------------------------------
__global__ __launch_bounds__(256)
void out_kernel(const float* __restrict__ hnext,   // hout + NCH
                float* __restrict__ out, int n4) {
    const float L2E = 1.44269504088896340736f;
    int stride = gridDim.x * blockDim.x;
    for (int i = blockIdx.x * blockDim.x + threadIdx.x; i < n4; i += stride) {
        float4 h = reinterpret_cast<const float4*>(hnext)[i];
        float4 o;
        o.x = h.x * h.x * __builtin_amdgcn_rcpf(1.0f + __builtin_amdgcn_exp2f(-L2E * h.x));
        o.y = h.y * h.y * __builtin_amdgcn_rcpf(1.0f + __builtin_amdgcn_exp2f(-L2E * h.y));
        o.z = h.z * h.z * __builtin_amdgcn_rcpf(1.0f + __builtin_amdgcn_exp2f(-L2E * h.z));
        o.w = h.w * h.w * __builtin_amdgcn_rcpf(1.0f + __builtin_amdgcn_exp2f(-L2E * h.w));
        reinterpret_cast<float4*>(out)[i] = o;
    }
}

// ---------------------------------------------------------------------------
extern "C" void kernel_launch(void* const* d_in, const int* in_sizes, int n_in,
                              void* d_out, int out_size, void* d_ws, size_t ws_size,
                              hipStream_t stream) {
    const float* x       = (const float*)d_in[0];  // [T,B,D]
    const float* h0      = (const float*)d_in[1];  // [B,D]
    const float* W_alpha = (const float*)d_in[2];  // [D,D]
    const float* b_alpha = (const float*)d_in[3];  // [D]
    const float* W_x     = (const float*)d_in[4];  // [D,D]
    const float* b       = (const float*)d_in[5];  // [D]

    float* out  = (float*)d_out;                              // [T,B,D]
    float* hout = out + (size_t)T_STEPS * BATCH * D_DIM;      // [T+1,B,D]

    // Workspace layout (~164 MB):
    //   alpha fp32 (64 MB) | wx fp32 (64 MB) | x bf16 (32 MB) | Wc bf16 (4 MB)
    float* ws_alpha = (float*)d_ws;
    float* ws_wx    = ws_alpha + (size_t)M_ROWS * D_DIM;
    unsigned short* ws_x = (unsigned short*)(ws_wx + (size_t)M_ROWS * D_DIM);
    unsigned short* ws_W = ws_x + (size_t)M_ROWS * K_DIM;

    // 1) convert x, W_alpha, W_x to bf16
    {
        int n4 = M_ROWS * K_DIM / 4;
        cvt_bf16_kernel<<<(n4 + 255) / 256, 256, 0, stream>>>(x, ws_x, n4);
    }
    {
        int n4 = D_DIM * K_DIM / 4;
        cvt_bf16_kernel<<<(n4 + 255) / 256, 256, 0, stream>>>(W_alpha, ws_W, n4);
        cvt_bf16_kernel<<<(n4 + 255) / 256, 256, 0, stream>>>(
            W_x, ws_W + (size_t)D_DIM * K_DIM, n4);
    }

    // 2) fused GEMM (N = 2048 covers both projections) + bias + sigmoid epilogue
    {
        dim3 grid(N_COLS / BN, M_ROWS / BM);   // (16, 128)
        gemm_kernel<<<grid, 256, 0, stream>>>(ws_x, ws_W, b_alpha, b,
                                              ws_alpha, ws_wx);
    }

    // 3) sequential scan: 128 blocks x 1 wave, LDS double-buffer, counted vmcnt
    scan_kernel<<<NCH / 64, 64, 0, stream>>>(ws_alpha, ws_wx, h0, hout);

    // 4) out = h*silu(h), massively parallel from hout (shifted one row)
    {
        int n4 = (int)((size_t)T_STEPS * NCH / 4);
        out_kernel<<<2048, 256, 0, stream>>>(hout + NCH, out, n4);
    }
}

// Round 5
// 362.120 us; speedup vs baseline: 1.1739x; 1.1491x over previous
//
#include <hip/hip_runtime.h>
#include <hip/hip_bf16.h>
#include <cstdint>
#include <cstddef>

// Problem dims (fixed by the reference)
#define T_STEPS 2048
#define BATCH   8
#define D_DIM   1024
#define M_ROWS  (T_STEPS * BATCH)   // 16384 rows of x
#define N_COLS  (2 * D_DIM)         // 2048: W_alpha rows ++ W_x rows
#define K_DIM   D_DIM               // 1024
#define NCH     (BATCH * D_DIM)     // 8192 independent recurrence channels

// GEMM tiling (m97 pattern: unpadded LDS, global_load_lds staging)
#define BM 128
#define BN 128
#define BK 32

typedef __bf16 bf16x8 __attribute__((ext_vector_type(8)));
typedef float  f32x4  __attribute__((ext_vector_type(4)));

__device__ __forceinline__ unsigned short f2bf_rne(float f) {
    union { float f; unsigned u; } c; c.f = f;
    unsigned u = c.u;
    u += 0x7fffu + ((u >> 16) & 1u);   // round-to-nearest-even (inputs finite)
    return (unsigned short)(u >> 16);
}

__device__ __forceinline__ float sigmoid_f(float z) {
    return 1.0f / (1.0f + __expf(-z));
}

// async global -> LDS DMA, 16 B per lane; LDS dest = wave-uniform base + lane*16
__device__ __forceinline__ void glds16(const void* gptr, void* lptr) {
    __builtin_amdgcn_global_load_lds(
        (const __attribute__((address_space(1))) unsigned int*)gptr,
        (__attribute__((address_space(3))) unsigned int*)lptr,
        16, 0, 0);
}

// ---------------------------------------------------------------------------
// fp32 -> bf16 convert (vectorized x4)
// ---------------------------------------------------------------------------
__global__ void cvt_bf16_kernel(const float* __restrict__ src,
                                unsigned short* __restrict__ dst, int n4) {
    int i = blockIdx.x * blockDim.x + threadIdx.x;
    if (i >= n4) return;
    float4 v = reinterpret_cast<const float4*>(src)[i];
    ushort4 o;
    o.x = f2bf_rne(v.x); o.y = f2bf_rne(v.y);
    o.z = f2bf_rne(v.z); o.w = f2bf_rne(v.w);
    reinterpret_cast<ushort4*>(dst)[i] = o;
}

// ---------------------------------------------------------------------------
// Fused bf16 MFMA GEMM (m97 structure): out[m,n] = sum_k x[m,k] * Wc[n,k]
//   n <  1024 -> alpha_out[m,n]   = sigmoid(acc + b_alpha[n])
//   n >= 1024 -> wx_out[m,n-1024] = acc + b[n-1024]
// 256 thr = 4 waves; tile 128x128, BK=32; wave = 64x64 (4x4 MFMA tiles).
// XCD-bijective swizzle (T1): nwg=2048 (%8==0).
// ---------------------------------------------------------------------------
__global__ __launch_bounds__(256, 2)
void gemm_kernel(const unsigned short* __restrict__ A,   // [M][K] bf16 (x)
                 const unsigned short* __restrict__ Bm,  // [N][K] bf16 (W_alpha ++ W_x)
                 const float* __restrict__ b_alpha,      // [D]
                 const float* __restrict__ b_x,          // [D]
                 float* __restrict__ alpha_out,          // [M][D] fp32
                 float* __restrict__ wx_out)             // [M][D] fp32
{
    __shared__ unsigned short sA[BM * BK];   // 8 KB
    __shared__ unsigned short sB[BN * BK];   // 8 KB

    const int tid  = threadIdx.x;
    const int wave = tid >> 6;
    const int lane = tid & 63;

    // XCD swizzle: grid is (16, 128) = 2048 wgs; 2048 % 8 == 0 -> bijective
    const int orig = blockIdx.y * 16 + blockIdx.x;
    const int swz  = (orig & 7) * 256 + (orig >> 3);
    const int rowBase = (swz >> 4) * BM;
    const int colBase = (swz & 15) * BN;

    const int wr = (wave >> 1) * 64;
    const int wc = (wave & 1) * 64;

    const int laneHi = lane >> 4;           // 0..3
    const int laneLo = lane & 15;

    // DMA staging addresses (per lane): row sub-offset + col offset
    const int dRow = lane >> 2;             // 0..15
    const int dCol = (lane & 3) * 8;        // 0,8,16,24

    f32x4 acc[4][4];
#pragma unroll
    for (int i = 0; i < 4; i++)
#pragma unroll
        for (int j = 0; j < 4; j++)
            acc[i][j] = (f32x4)(0.0f);

    for (int k0 = 0; k0 < K_DIM; k0 += BK) {
#pragma unroll
        for (int p = 0; p < 2; ++p) {
            const int seg = wave * 2 + p;   // 16-row segment index, 0..7
            glds16(A + (size_t)(rowBase + seg * 16 + dRow) * K_DIM + k0 + dCol,
                   &sA[seg * 512]);
            glds16(Bm + (size_t)(colBase + seg * 16 + dRow) * K_DIM + k0 + dCol,
                   &sB[seg * 512]);
        }
        __syncthreads();   // compiler drains vmcnt(0) here -> LDS tiles ready

        bf16x8 af[4], bfr[4];
#pragma unroll
        for (int i = 0; i < 4; i++)
            af[i] = *reinterpret_cast<const bf16x8*>(
                &sA[(wr + i * 16 + laneLo) * BK + laneHi * 8]);
#pragma unroll
        for (int j = 0; j < 4; j++)
            bfr[j] = *reinterpret_cast<const bf16x8*>(
                &sB[(wc + j * 16 + laneLo) * BK + laneHi * 8]);
        __syncthreads();   // fragments in regs; LDS free for next k-step

#pragma unroll
        for (int i = 0; i < 4; i++)
#pragma unroll
            for (int j = 0; j < 4; j++)
                acc[i][j] = __builtin_amdgcn_mfma_f32_16x16x32_bf16(
                    af[i], bfr[j], acc[i][j], 0, 0, 0);
    }

    // Epilogue. C/D layout: col = lane&15, row = (lane>>4)*4 + reg  [m89/m91]
#pragma unroll
    for (int i = 0; i < 4; i++) {
        int row = rowBase + wr + i * 16 + laneHi * 4;
#pragma unroll
        for (int j = 0; j < 4; j++) {
            int col = colBase + wc + j * 16 + laneLo;
            if (col < D_DIM) {
                float bias = b_alpha[col];
#pragma unroll
                for (int r = 0; r < 4; r++) {
                    float z = acc[i][j][r] + bias;
                    alpha_out[(size_t)(row + r) * D_DIM + col] = sigmoid_f(z);
                }
            } else {
                int c2 = col - D_DIM;
                float bias = b_x[c2];
#pragma unroll
                for (int r = 0; r < 4; r++)
                    wx_out[(size_t)(row + r) * D_DIM + c2] = acc[i][j][r] + bias;
            }
        }
    }
}

// ---------------------------------------------------------------------------
// Sequential scan v5: 3-wave producer/compute/consumer role split.
//   128 blocks x 192 threads (3 waves), 64 channels/block, 1 ch/lane.
//   wave0 COMPUTE : pure LDS+VALU loop, zero VMEM ops -> never stalls on vmcnt.
//   wave1 LOADER  : pure glds16 FIFO -> counted vmcnt expresses 3-tiles-ahead
//                   prefetch (48 outstanding <= 63). In-flight 48 KB/block
//                   (6 MB chip-wide) -> Little's-law throughput >> demand.
//                   (Rounds 1-3 all hit ~4700 cy/tile = glds latency ~9000 cy
//                   under load with only 1-tile-deep pipeline; stores sharing
//                   the compute wave's in-order vmcnt FIFO capped the depth.)
//   wave2 STORER  : drains h from LDS ring, writes hout AND fused
//                   out = h^2*sigmoid(h)  -> out_kernel eliminated.
//   Sync: raw s_barrier per tile (NO __syncthreads -> no vmcnt(0) drain);
//   wave0 lgkmcnt(0)+sched_barrier(0) before barrier for sH visibility.
//   Deadlock audit (R4): barrier count uniform across waves (NT+1 each);
//   every vmcnt(N) has N <= provable outstanding count; ring write target
//   (t+3)&3 == (t-1)&3 was consumed before this iteration's barrier.
// Recurrence (5-op cross-step chain):
//   u = 1-a; p = C*(h+w); e = exp2(p); r = rcp(e+1); m = a*h+u; h' = m - 2u*r
// LDS: in[4][2][TT*64] fp32 ring (64 KB), sH[2][TT*64] (16 KB).
// ---------------------------------------------------------------------------
#define TT  32
#define NT  (T_STEPS / TT)   // 64 tiles
#define PF  3                // prefetch distance (tiles)

__global__ __launch_bounds__(192)
void scan_kernel(const float* __restrict__ alpha,  // [T][NCH]
                 const float* __restrict__ wx,     // [T][NCH]
                 const float* __restrict__ h0,     // [NCH]
                 float* __restrict__ out,          // [T][NCH]
                 float* __restrict__ hout)         // [T+1][NCH]
{
    __shared__ float sIn[4][2][TT * 64];   // [buf][0=alpha,1=wx]  64 KB
    __shared__ float sH[2][TT * 64];       // h ring               16 KB

    const int lane = threadIdx.x & 63;
    const int wid  = threadIdx.x >> 6;
    const int ch0  = blockIdx.x * 64;

    const float C2L = 2.88539008177792681472f;   // 2*log2(e)

    // loader lane mapping (16 B per lane): ts sub-offset + channel offset
    const int q  = lane >> 4;            // 0..3  (timestep within glds16)
    const int c4 = (lane & 15) * 4;      // channel group

    // storer lane mapping: 16 lanes per timestep, float4 of channels
    const int tq  = lane >> 4;           // 0..3
    const int c4s = (lane & 15) * 4;

    float h = 0.0f;

    // ---- prologue ----
    if (wid == 1) {
        // stage tiles 0..PF-1
#pragma unroll
        for (int t = 0; t < PF; ++t)
#pragma unroll
            for (int p = 0; p < TT / 4; ++p) {
                const size_t g = (size_t)(t * TT + p * 4 + q) * NCH + ch0 + c4;
                glds16(alpha + g, &sIn[t][0][p * 256]);
                glds16(wx    + g, &sIn[t][1][p * 256]);
            }
        // drain G_0 only (G_1, G_2 = 32 ops stay in flight)
        asm volatile("s_waitcnt vmcnt(32)" ::: "memory");
    } else if (wid == 0) {
        h = h0[ch0 + lane];
    } else {
        hout[ch0 + lane] = h0[ch0 + lane];   // row 0
    }
    __builtin_amdgcn_s_barrier();
    __builtin_amdgcn_sched_barrier(0);

    // ---- main loop: one barrier per tile ----
    for (int tile = 0; tile < NT; ++tile) {
        if (wid == 0) {
            // COMPUTE tile `tile` from sIn[tile&3]; h trace -> sH[tile&1]
            const float* sA  = &sIn[tile & 3][0][0];
            const float* sW  = &sIn[tile & 3][1][0];
            float* sHc       = &sH[tile & 1][0];
#pragma unroll 8
            for (int ts = 0; ts < TT; ++ts) {
                const float a = sA[ts * 64 + lane];
                const float w = sW[ts * 64 + lane];
                const float u = 1.0f - a;
                const float p = (h + w) * C2L;
                const float e = __builtin_amdgcn_exp2f(p);
                const float r = __builtin_amdgcn_rcpf(e + 1.0f);
                const float m = fmaf(a, h, u);
                h = fmaf(-(u + u), r, m);
                sHc[ts * 64 + lane] = h;
            }
            asm volatile("s_waitcnt lgkmcnt(0)" ::: "memory");
            __builtin_amdgcn_sched_barrier(0);
        } else if (wid == 1) {
            // LOADER: stage tile+PF, then guarantee tile+1 is resident
            if (tile + PF < NT) {
                const int b  = (tile + PF) & 3;
                const int t0 = (tile + PF) * TT;
#pragma unroll
                for (int p = 0; p < TT / 4; ++p) {
                    const size_t g = (size_t)(t0 + p * 4 + q) * NCH + ch0 + c4;
                    glds16(alpha + g, &sIn[b][0][p * 256]);
                    glds16(wx    + g, &sIn[b][1][p * 256]);
                }
            }
            // pure-glds FIFO: drain down to the bursts younger than G_{tile+1}
            if (tile + PF < NT) {
                asm volatile("s_waitcnt vmcnt(32)" ::: "memory");
            } else if (tile + PF == NT) {         // bursts t+1, t+2 outstanding
                asm volatile("s_waitcnt vmcnt(16)" ::: "memory");
            } else if (tile + 1 < NT) {           // only burst t+1 outstanding
                asm volatile("s_waitcnt vmcnt(0)" ::: "memory");
            }
            __builtin_amdgcn_sched_barrier(0);
        } else {
            // STORER: flush tile-1's h trace; fused out = h^2 * sigmoid(h)
            if (tile >= 1) {
                const float* sHs = &sH[(tile - 1) & 1][0];
                const int tb = (tile - 1) * TT;
#pragma unroll
                for (int i = 0; i < TT / 4; ++i) {
                    const int tsrow = i * 4 + tq;
                    const float4 hv = *reinterpret_cast<const float4*>(
                        &sHs[tsrow * 64 + c4s]);
                    *reinterpret_cast<float4*>(
                        &hout[(size_t)(tb + tsrow + 1) * NCH + ch0 + c4s]) = hv;
                    float4 o;
                    o.x = hv.x * hv.x * sigmoid_f(hv.x);
                    o.y = hv.y * hv.y * sigmoid_f(hv.y);
                    o.z = hv.z * hv.z * sigmoid_f(hv.z);
                    o.w = hv.w * hv.w * sigmoid_f(hv.w);
                    *reinterpret_cast<float4*>(
                        &out[(size_t)(tb + tsrow) * NCH + ch0 + c4s]) = o;
                }
            }
        }
        __builtin_amdgcn_s_barrier();
        __builtin_amdgcn_sched_barrier(0);
    }

    // ---- epilogue: flush final tile ----
    if (wid == 2) {
        const float* sHs = &sH[(NT - 1) & 1][0];
        const int tb = (NT - 1) * TT;
#pragma unroll
        for (int i = 0; i < TT / 4; ++i) {
            const int tsrow = i * 4 + tq;
            const float4 hv = *reinterpret_cast<const float4*>(
                &sHs[tsrow * 64 + c4s]);
            *reinterpret_cast<float4*>(
                &hout[(size_t)(tb + tsrow + 1) * NCH + ch0 + c4s]) = hv;
            float4 o;
            o.x = hv.x * hv.x * sigmoid_f(hv.x);
            o.y = hv.y * hv.y * sigmoid_f(hv.y);
            o.z = hv.z * hv.z * sigmoid_f(hv.z);
            o.w = hv.w * hv.w * sigmoid_f(hv.w);
            *reinterpret_cast<float4*>(
                &out[(size_t)(tb + tsrow) * NCH + ch0 + c4s]) = o;
        }
    }
}

// ---------------------------------------------------------------------------
extern "C" void kernel_launch(void* const* d_in, const int* in_sizes, int n_in,
                              void* d_out, int out_size, void* d_ws, size_t ws_size,
                              hipStream_t stream) {
    const float* x       = (const float*)d_in[0];  // [T,B,D]
    const float* h0      = (const float*)d_in[1];  // [B,D]
    const float* W_alpha = (const float*)d_in[2];  // [D,D]
    const float* b_alpha = (const float*)d_in[3];  // [D]
    const float* W_x     = (const float*)d_in[4];  // [D,D]
    const float* b       = (const float*)d_in[5];  // [D]

    float* out  = (float*)d_out;                              // [T,B,D]
    float* hout = out + (size_t)T_STEPS * BATCH * D_DIM;      // [T+1,B,D]

    // Workspace layout (~164 MB):
    //   alpha fp32 (64 MB) | wx fp32 (64 MB) | x bf16 (32 MB) | Wc bf16 (4 MB)
    float* ws_alpha = (float*)d_ws;
    float* ws_wx    = ws_alpha + (size_t)M_ROWS * D_DIM;
    unsigned short* ws_x = (unsigned short*)(ws_wx + (size_t)M_ROWS * D_DIM);
    unsigned short* ws_W = ws_x + (size_t)M_ROWS * K_DIM;

    // 1) convert x, W_alpha, W_x to bf16
    {
        int n4 = M_ROWS * K_DIM / 4;
        cvt_bf16_kernel<<<(n4 + 255) / 256, 256, 0, stream>>>(x, ws_x, n4);
    }
    {
        int n4 = D_DIM * K_DIM / 4;
        cvt_bf16_kernel<<<(n4 + 255) / 256, 256, 0, stream>>>(W_alpha, ws_W, n4);
        cvt_bf16_kernel<<<(n4 + 255) / 256, 256, 0, stream>>>(
            W_x, ws_W + (size_t)D_DIM * K_DIM, n4);
    }

    // 2) fused GEMM (N = 2048 covers both projections) + bias + sigmoid epilogue
    {
        dim3 grid(N_COLS / BN, M_ROWS / BM);   // (16, 128)
        gemm_kernel<<<grid, 256, 0, stream>>>(ws_x, ws_W, b_alpha, b,
                                              ws_alpha, ws_wx);
    }

    // 3) sequential scan: 128 blocks x 3 waves (loader / compute / storer),
    //    out fused into the storer wave -> no separate out_kernel
    scan_kernel<<<NCH / 64, 192, 0, stream>>>(ws_alpha, ws_wx, h0, out, hout);
}

// Round 6
// 360.842 us; speedup vs baseline: 1.1780x; 1.0035x over previous
//
#include <hip/hip_runtime.h>
#include <hip/hip_bf16.h>
#include <cstdint>
#include <cstddef>

// Problem dims (fixed by the reference)
#define T_STEPS 2048
#define BATCH   8
#define D_DIM   1024
#define M_ROWS  (T_STEPS * BATCH)   // 16384 rows of x
#define N_COLS  (2 * D_DIM)         // 2048: W_alpha rows ++ W_x rows
#define K_DIM   D_DIM               // 1024
#define NCH     (BATCH * D_DIM)     // 8192 independent recurrence channels

// GEMM tiling (m97 pattern: unpadded LDS, global_load_lds staging)
#define BM 128
#define BN 128
#define BK 32

typedef __bf16 bf16x8 __attribute__((ext_vector_type(8)));
typedef float  f32x4  __attribute__((ext_vector_type(4)));

__device__ __forceinline__ unsigned short f2bf_rne(float f) {
    union { float f; unsigned u; } c; c.f = f;
    unsigned u = c.u;
    u += 0x7fffu + ((u >> 16) & 1u);   // round-to-nearest-even (inputs finite)
    return (unsigned short)(u >> 16);
}

__device__ __forceinline__ float sigmoid_f(float z) {
    return 1.0f / (1.0f + __expf(-z));
}

// async global -> LDS DMA, 16 B per lane; LDS dest = wave-uniform base + lane*16
__device__ __forceinline__ void glds16(const void* gptr, void* lptr) {
    __builtin_amdgcn_global_load_lds(
        (const __attribute__((address_space(1))) unsigned int*)gptr,
        (__attribute__((address_space(3))) unsigned int*)lptr,
        16, 0, 0);
}

// ---------------------------------------------------------------------------
// fp32 -> bf16 convert (vectorized x4)
// ---------------------------------------------------------------------------
__global__ void cvt_bf16_kernel(const float* __restrict__ src,
                                unsigned short* __restrict__ dst, int n4) {
    int i = blockIdx.x * blockDim.x + threadIdx.x;
    if (i >= n4) return;
    float4 v = reinterpret_cast<const float4*>(src)[i];
    ushort4 o;
    o.x = f2bf_rne(v.x); o.y = f2bf_rne(v.y);
    o.z = f2bf_rne(v.z); o.w = f2bf_rne(v.w);
    reinterpret_cast<ushort4*>(dst)[i] = o;
}

// ---------------------------------------------------------------------------
// Fused bf16 MFMA GEMM (m97 structure): out[m,n] = sum_k x[m,k] * Wc[n,k]
//   n <  1024 -> alpha_out[m,n]   = sigmoid(acc + b_alpha[n])
//   n >= 1024 -> wx_out[m,n-1024] = acc + b[n-1024]
// 256 thr = 4 waves; tile 128x128, BK=32; wave = 64x64 (4x4 MFMA tiles).
// XCD-bijective swizzle (T1): nwg=2048 (%8==0).
// ---------------------------------------------------------------------------
__global__ __launch_bounds__(256, 2)
void gemm_kernel(const unsigned short* __restrict__ A,   // [M][K] bf16 (x)
                 const unsigned short* __restrict__ Bm,  // [N][K] bf16 (W_alpha ++ W_x)
                 const float* __restrict__ b_alpha,      // [D]
                 const float* __restrict__ b_x,          // [D]
                 float* __restrict__ alpha_out,          // [M][D] fp32
                 float* __restrict__ wx_out)             // [M][D] fp32
{
    __shared__ unsigned short sA[BM * BK];   // 8 KB
    __shared__ unsigned short sB[BN * BK];   // 8 KB

    const int tid  = threadIdx.x;
    const int wave = tid >> 6;
    const int lane = tid & 63;

    // XCD swizzle: grid is (16, 128) = 2048 wgs; 2048 % 8 == 0 -> bijective
    const int orig = blockIdx.y * 16 + blockIdx.x;
    const int swz  = (orig & 7) * 256 + (orig >> 3);
    const int rowBase = (swz >> 4) * BM;
    const int colBase = (swz & 15) * BN;

    const int wr = (wave >> 1) * 64;
    const int wc = (wave & 1) * 64;

    const int laneHi = lane >> 4;           // 0..3
    const int laneLo = lane & 15;

    // DMA staging addresses (per lane): row sub-offset + col offset
    const int dRow = lane >> 2;             // 0..15
    const int dCol = (lane & 3) * 8;        // 0,8,16,24

    f32x4 acc[4][4];
#pragma unroll
    for (int i = 0; i < 4; i++)
#pragma unroll
        for (int j = 0; j < 4; j++)
            acc[i][j] = (f32x4)(0.0f);

    for (int k0 = 0; k0 < K_DIM; k0 += BK) {
#pragma unroll
        for (int p = 0; p < 2; ++p) {
            const int seg = wave * 2 + p;   // 16-row segment index, 0..7
            glds16(A + (size_t)(rowBase + seg * 16 + dRow) * K_DIM + k0 + dCol,
                   &sA[seg * 512]);
            glds16(Bm + (size_t)(colBase + seg * 16 + dRow) * K_DIM + k0 + dCol,
                   &sB[seg * 512]);
        }
        __syncthreads();   // compiler drains vmcnt(0) here -> LDS tiles ready

        bf16x8 af[4], bfr[4];
#pragma unroll
        for (int i = 0; i < 4; i++)
            af[i] = *reinterpret_cast<const bf16x8*>(
                &sA[(wr + i * 16 + laneLo) * BK + laneHi * 8]);
#pragma unroll
        for (int j = 0; j < 4; j++)
            bfr[j] = *reinterpret_cast<const bf16x8*>(
                &sB[(wc + j * 16 + laneLo) * BK + laneHi * 8]);
        __syncthreads();   // fragments in regs; LDS free for next k-step

#pragma unroll
        for (int i = 0; i < 4; i++)
#pragma unroll
            for (int j = 0; j < 4; j++)
                acc[i][j] = __builtin_amdgcn_mfma_f32_16x16x32_bf16(
                    af[i], bfr[j], acc[i][j], 0, 0, 0);
    }

    // Epilogue. C/D layout: col = lane&15, row = (lane>>4)*4 + reg  [m89/m91]
#pragma unroll
    for (int i = 0; i < 4; i++) {
        int row = rowBase + wr + i * 16 + laneHi * 4;
#pragma unroll
        for (int j = 0; j < 4; j++) {
            int col = colBase + wc + j * 16 + laneLo;
            if (col < D_DIM) {
                float bias = b_alpha[col];
#pragma unroll
                for (int r = 0; r < 4; r++) {
                    float z = acc[i][j][r] + bias;
                    alpha_out[(size_t)(row + r) * D_DIM + col] = sigmoid_f(z);
                }
            } else {
                int c2 = col - D_DIM;
                float bias = b_x[c2];
#pragma unroll
                for (int r = 0; r < 4; r++)
                    wx_out[(size_t)(row + r) * D_DIM + c2] = acc[i][j][r] + bias;
            }
        }
    }
}

// ---------------------------------------------------------------------------
// Sequential scan v6: 3-wave role split, 256 blocks x 32 channels.
//   R5 analysis: v5 (128 blocks x 64 ch) was per-CU-bandwidth bound --
//   3.1 MB/block over ~90 us = 34 GB/s/CU, above the 24.6 GB/s/CU chip
//   fair-share, with only half the CUs active. v6 doubles active CUs;
//   per-block traffic halves to 1.55 MB -> BW floor ~29 us, compute floor
//   ~27 us (5-op chain ~25-30 cy/step).
//   wave0 COMPUTE : 32 active lanes, 1 ch/lane; pure LDS+VALU.
//   wave1 LOADER  : pure glds16 FIFO; PF=6 tiles ahead (48 outstanding <=63,
//                   48 KB/block in flight, 12 MB chip-wide).
//   wave2 STORER  : drains h from sH ring -> hout + fused out = h^2*sigmoid(h).
//   Sync: raw s_barrier per tile; counted vmcnt only (never 0 mid-loop).
// LDS: sIn[8][2][32*32] fp32 ring (64 KB); sH[2][32*36] (stride-36 pad so
// storer's float4 reads are 2-way, 9 KB).
// Tile = TT=32 timesteps x 32 ch x 4 B = 4 KB per array = 4 glds16 per array.
// Loader lane map: ts = p*8 + l/8, ch4 = (l&7)*4  (LDS linear == row-major).
// ---------------------------------------------------------------------------
#define TT   32
#define NT   (T_STEPS / TT)   // 64 tiles
#define PF   6                // prefetch distance (tiles)
#define CPB  32               // channels per block
#define SHS  36               // sH row stride (floats), padded

__global__ __launch_bounds__(192)
void scan_kernel(const float* __restrict__ alpha,  // [T][NCH]
                 const float* __restrict__ wx,     // [T][NCH]
                 const float* __restrict__ h0,     // [NCH]
                 float* __restrict__ out,          // [T][NCH]
                 float* __restrict__ hout)         // [T+1][NCH]
{
    __shared__ float sIn[8][2][TT * CPB];   // [buf][0=alpha,1=wx]  64 KB
    __shared__ float sH[2][TT * SHS];       // h ring, padded       9 KB

    const int lane = threadIdx.x & 63;
    const int wid  = threadIdx.x >> 6;
    const int ch0  = blockIdx.x * CPB;

    const float C2L = 2.88539008177792681472f;   // 2*log2(e)

    // loader/storer lane mapping (16 B per lane): 8 lanes per timestep
    const int q8 = lane >> 3;            // timestep sub-offset 0..7
    const int c4 = (lane & 7) * 4;       // channel group

    float h = 0.0f;

    // ---- prologue ----
    if (wid == 1) {
        // stage tiles 0..PF-1 (6 bursts x 8 ops = 48 outstanding)
#pragma unroll
        for (int t = 0; t < PF; ++t)
#pragma unroll
            for (int p = 0; p < TT / 8; ++p) {
                const size_t g = (size_t)(t * TT + p * 8 + q8) * NCH + ch0 + c4;
                glds16(alpha + g, &sIn[t][0][p * 256]);
                glds16(wx    + g, &sIn[t][1][p * 256]);
            }
        // complete G_0; keep G_1..G_5 (40 ops) in flight
        asm volatile("s_waitcnt vmcnt(40)" ::: "memory");
    } else if (wid == 0) {
        if (lane < CPB) h = h0[ch0 + lane];
    } else {
        if (lane < CPB) hout[ch0 + lane] = h0[ch0 + lane];   // row 0
    }
    __builtin_amdgcn_s_barrier();
    __builtin_amdgcn_sched_barrier(0);

    // ---- main loop: one barrier per tile ----
    for (int tile = 0; tile < NT; ++tile) {
        if (wid == 0) {
            // COMPUTE tile from sIn[tile&7]; h trace -> sH[tile&1]
            const float* sA  = &sIn[tile & 7][0][0];
            const float* sW  = &sIn[tile & 7][1][0];
            float* sHc       = &sH[tile & 1][0];
            if (lane < CPB) {
#pragma unroll 8
                for (int ts = 0; ts < TT; ++ts) {
                    const float a = sA[ts * CPB + lane];
                    const float w = sW[ts * CPB + lane];
                    const float u = 1.0f - a;
                    const float p = (h + w) * C2L;
                    const float e = __builtin_amdgcn_exp2f(p);
                    const float r = __builtin_amdgcn_rcpf(e + 1.0f);
                    const float m = fmaf(a, h, u);
                    h = fmaf(-(u + u), r, m);
                    sHc[ts * SHS + lane] = h;
                }
            }
            asm volatile("s_waitcnt lgkmcnt(0)" ::: "memory");
            __builtin_amdgcn_sched_barrier(0);
        } else if (wid == 1) {
            // LOADER: stage tile+PF, then guarantee tile+1 is resident
            if (tile + PF < NT) {
                const int b  = (tile + PF) & 7;
                const int t0 = (tile + PF) * TT;
#pragma unroll
                for (int p = 0; p < TT / 8; ++p) {
                    const size_t g = (size_t)(t0 + p * 8 + q8) * NCH + ch0 + c4;
                    glds16(alpha + g, &sIn[b][0][p * 256]);
                    glds16(wx    + g, &sIn[b][1][p * 256]);
                }
            }
            // counted drain: leave (count-1) bursts in flight, count =
            // min(PF, NT-1-tile) bursts outstanding after issue
            {
                const int rem = NT - 1 - tile;
                if (rem >= PF) {
                    asm volatile("s_waitcnt vmcnt(40)" ::: "memory");
                } else if (rem == 5) {
                    asm volatile("s_waitcnt vmcnt(32)" ::: "memory");
                } else if (rem == 4) {
                    asm volatile("s_waitcnt vmcnt(24)" ::: "memory");
                } else if (rem == 3) {
                    asm volatile("s_waitcnt vmcnt(16)" ::: "memory");
                } else if (rem == 2) {
                    asm volatile("s_waitcnt vmcnt(8)" ::: "memory");
                } else if (rem == 1) {
                    asm volatile("s_waitcnt vmcnt(0)" ::: "memory");
                }   // rem == 0: nothing outstanding
            }
            __builtin_amdgcn_sched_barrier(0);
        } else {
            // STORER: flush tile-1's h trace; fused out = h^2 * sigmoid(h)
            if (tile >= 1) {
                const float* sHs = &sH[(tile - 1) & 1][0];
                const int tb = (tile - 1) * TT;
#pragma unroll
                for (int i = 0; i < TT / 8; ++i) {
                    const int tsrow = i * 8 + q8;
                    const float4 hv = *reinterpret_cast<const float4*>(
                        &sHs[tsrow * SHS + c4]);
                    *reinterpret_cast<float4*>(
                        &hout[(size_t)(tb + tsrow + 1) * NCH + ch0 + c4]) = hv;
                    float4 o;
                    o.x = hv.x * hv.x * sigmoid_f(hv.x);
                    o.y = hv.y * hv.y * sigmoid_f(hv.y);
                    o.z = hv.z * hv.z * sigmoid_f(hv.z);
                    o.w = hv.w * hv.w * sigmoid_f(hv.w);
                    *reinterpret_cast<float4*>(
                        &out[(size_t)(tb + tsrow) * NCH + ch0 + c4]) = o;
                }
            }
        }
        __builtin_amdgcn_s_barrier();
        __builtin_amdgcn_sched_barrier(0);
    }

    // ---- epilogue: flush final tile ----
    if (wid == 2) {
        const float* sHs = &sH[(NT - 1) & 1][0];
        const int tb = (NT - 1) * TT;
#pragma unroll
        for (int i = 0; i < TT / 8; ++i) {
            const int tsrow = i * 8 + q8;
            const float4 hv = *reinterpret_cast<const float4*>(
                &sHs[tsrow * SHS + c4]);
            *reinterpret_cast<float4*>(
                &hout[(size_t)(tb + tsrow + 1) * NCH + ch0 + c4]) = hv;
            float4 o;
            o.x = hv.x * hv.x * sigmoid_f(hv.x);
            o.y = hv.y * hv.y * sigmoid_f(hv.y);
            o.z = hv.z * hv.z * sigmoid_f(hv.z);
            o.w = hv.w * hv.w * sigmoid_f(hv.w);
            *reinterpret_cast<float4*>(
                &out[(size_t)(tb + tsrow) * NCH + ch0 + c4]) = o;
        }
    }
}

// ---------------------------------------------------------------------------
extern "C" void kernel_launch(void* const* d_in, const int* in_sizes, int n_in,
                              void* d_out, int out_size, void* d_ws, size_t ws_size,
                              hipStream_t stream) {
    const float* x       = (const float*)d_in[0];  // [T,B,D]
    const float* h0      = (const float*)d_in[1];  // [B,D]
    const float* W_alpha = (const float*)d_in[2];  // [D,D]
    const float* b_alpha = (const float*)d_in[3];  // [D]
    const float* W_x     = (const float*)d_in[4];  // [D,D]
    const float* b       = (const float*)d_in[5];  // [D]

    float* out  = (float*)d_out;                              // [T,B,D]
    float* hout = out + (size_t)T_STEPS * BATCH * D_DIM;      // [T+1,B,D]

    // Workspace layout (~164 MB):
    //   alpha fp32 (64 MB) | wx fp32 (64 MB) | x bf16 (32 MB) | Wc bf16 (4 MB)
    float* ws_alpha = (float*)d_ws;
    float* ws_wx    = ws_alpha + (size_t)M_ROWS * D_DIM;
    unsigned short* ws_x = (unsigned short*)(ws_wx + (size_t)M_ROWS * D_DIM);
    unsigned short* ws_W = ws_x + (size_t)M_ROWS * K_DIM;

    // 1) convert x, W_alpha, W_x to bf16
    {
        int n4 = M_ROWS * K_DIM / 4;
        cvt_bf16_kernel<<<(n4 + 255) / 256, 256, 0, stream>>>(x, ws_x, n4);
    }
    {
        int n4 = D_DIM * K_DIM / 4;
        cvt_bf16_kernel<<<(n4 + 255) / 256, 256, 0, stream>>>(W_alpha, ws_W, n4);
        cvt_bf16_kernel<<<(n4 + 255) / 256, 256, 0, stream>>>(
            W_x, ws_W + (size_t)D_DIM * K_DIM, n4);
    }

    // 2) fused GEMM (N = 2048 covers both projections) + bias + sigmoid epilogue
    {
        dim3 grid(N_COLS / BN, M_ROWS / BM);   // (16, 128)
        gemm_kernel<<<grid, 256, 0, stream>>>(ws_x, ws_W, b_alpha, b,
                                              ws_alpha, ws_wx);
    }

    // 3) sequential scan: 256 blocks x 3 waves (loader / compute / storer),
    //    32 channels/block -> all 256 CUs active
    scan_kernel<<<NCH / CPB, 192, 0, stream>>>(ws_alpha, ws_wx, h0, out, hout);
}

// Round 8
// 347.615 us; speedup vs baseline: 1.2229x; 1.0381x over previous
//
#include <hip/hip_runtime.h>
#include <hip/hip_bf16.h>
#include <cstdint>
#include <cstddef>

// Problem dims (fixed by the reference)
#define T_STEPS 2048
#define BATCH   8
#define D_DIM   1024
#define M_ROWS  (T_STEPS * BATCH)   // 16384 rows of x
#define N_COLS  (2 * D_DIM)         // 2048: W_alpha rows ++ W_x rows
#define K_DIM   D_DIM               // 1024
#define NCH     (BATCH * D_DIM)     // 8192 independent recurrence channels

// GEMM tiling: 128x128 tile, BK=64 (half the barriers of BK=32)
#define BM 128
#define BN 128
#define BK 64

typedef __bf16 bf16x8 __attribute__((ext_vector_type(8)));
typedef float  f32x4  __attribute__((ext_vector_type(4)));

__device__ __forceinline__ unsigned short f2bf_rne(float f) {
    union { float f; unsigned u; } c; c.f = f;
    unsigned u = c.u;
    u += 0x7fffu + ((u >> 16) & 1u);   // round-to-nearest-even (inputs finite)
    return (unsigned short)(u >> 16);
}

__device__ __forceinline__ float sigmoid_f(float z) {
    return 1.0f / (1.0f + __expf(-z));
}

// async global -> LDS DMA, 16 B per lane; LDS dest = wave-uniform base + lane*16
__device__ __forceinline__ void glds16(const void* gptr, void* lptr) {
    __builtin_amdgcn_global_load_lds(
        (const __attribute__((address_space(1))) unsigned int*)gptr,
        (__attribute__((address_space(3))) unsigned int*)lptr,
        16, 0, 0);
}

// ---------------------------------------------------------------------------
// fp32 -> bf16 convert (vectorized x4)
// ---------------------------------------------------------------------------
__global__ void cvt_bf16_kernel(const float* __restrict__ src,
                                unsigned short* __restrict__ dst, int n4) {
    int i = blockIdx.x * blockDim.x + threadIdx.x;
    if (i >= n4) return;
    float4 v = reinterpret_cast<const float4*>(src)[i];
    ushort4 o;
    o.x = f2bf_rne(v.x); o.y = f2bf_rne(v.y);
    o.z = f2bf_rne(v.z); o.w = f2bf_rne(v.w);
    reinterpret_cast<ushort4*>(dst)[i] = o;
}

// ---------------------------------------------------------------------------
// Fused bf16 MFMA GEMM, BK=64 + block-XOR LDS swizzle.
//   out[m,n] = sum_k x[m,k] * Wc[n,k]
//   n <  1024 -> alpha_out = sigmoid(acc + b_alpha[n]); else wx_out = acc + b.
// Swizzle (rule #21 both-sides): LDS dest of glds16 is linear; the per-lane
// GLOBAL source fetches logical 16B-block lb = (lane&7) ^ (lane>>3) of its
// row, so physical LDS block pb holds lb = pb ^ (row&7). Reads XOR back:
// &sA[row*64 + (((kk*4)+laneHi) ^ (row&7))*8]. Row-group of 8 lanes still
// covers the full 128 B row (permuted) -> global coalescing unchanged.
// (R7 audit: both old and new read patterns are ~8 lanes/bank-quadruple --
// near the b128 structural floor -- so the main lever here is BK=64 halving
// the per-K-loop barrier count, not the conflict counter.)
// ---------------------------------------------------------------------------
__global__ __launch_bounds__(256, 2)
void gemm_kernel(const unsigned short* __restrict__ A,   // [M][K] bf16 (x)
                 const unsigned short* __restrict__ Bm,  // [N][K] bf16 (W_alpha ++ W_x)
                 const float* __restrict__ b_alpha,      // [D]
                 const float* __restrict__ b_x,          // [D]
                 float* __restrict__ alpha_out,          // [M][D] fp32
                 float* __restrict__ wx_out)             // [M][D] fp32
{
    __shared__ unsigned short sA[BM * BK];   // 16 KB
    __shared__ unsigned short sB[BN * BK];   // 16 KB

    const int tid  = threadIdx.x;
    const int wave = tid >> 6;
    const int lane = tid & 63;

    // XCD swizzle: grid is (16, 128) = 2048 wgs; 2048 % 8 == 0 -> bijective
    const int orig = blockIdx.y * 16 + blockIdx.x;
    const int swz  = (orig & 7) * 256 + (orig >> 3);
    const int rowBase = (swz >> 4) * BM;
    const int colBase = (swz & 15) * BN;

    const int wr = (wave >> 1) * 64;
    const int wc = (wave & 1) * 64;

    const int laneHi = lane >> 4;           // 0..3
    const int laneLo = lane & 15;
    const int rxor   = laneLo & 7;          // row&7 for fragment reads

    // DMA staging: 8 rows per glds16; source col block XOR-swizzled
    const int dRow   = lane >> 3;                    // 0..7
    const int dColSw = ((lane & 7) ^ dRow) * 8;      // shorts

    f32x4 acc[4][4];
#pragma unroll
    for (int i = 0; i < 4; i++)
#pragma unroll
        for (int j = 0; j < 4; j++)
            acc[i][j] = (f32x4)(0.0f);

    for (int k0 = 0; k0 < K_DIM; k0 += BK) {
#pragma unroll
        for (int p = 0; p < 4; ++p) {
            const int seg = wave * 4 + p;   // 8-row segment index, 0..15
            glds16(A + (size_t)(rowBase + seg * 8 + dRow) * K_DIM + k0 + dColSw,
                   &sA[seg * 512]);
            glds16(Bm + (size_t)(colBase + seg * 8 + dRow) * K_DIM + k0 + dColSw,
                   &sB[seg * 512]);
        }
        __syncthreads();   // drains vmcnt(0) -> LDS tiles ready

#pragma unroll
        for (int kk = 0; kk < 2; ++kk) {
            bf16x8 af[4], bfr[4];
#pragma unroll
            for (int i = 0; i < 4; i++) {
                const int row = wr + i * 16 + laneLo;
                af[i] = *reinterpret_cast<const bf16x8*>(
                    &sA[row * BK + (((kk << 2) + laneHi) ^ rxor) * 8]);
            }
#pragma unroll
            for (int j = 0; j < 4; j++) {
                const int row = wc + j * 16 + laneLo;
                bfr[j] = *reinterpret_cast<const bf16x8*>(
                    &sB[row * BK + (((kk << 2) + laneHi) ^ rxor) * 8]);
            }
#pragma unroll
            for (int i = 0; i < 4; i++)
#pragma unroll
                for (int j = 0; j < 4; j++)
                    acc[i][j] = __builtin_amdgcn_mfma_f32_16x16x32_bf16(
                        af[i], bfr[j], acc[i][j], 0, 0, 0);
        }
        __syncthreads();   // all reads done; LDS free for next k-step
    }

    // Epilogue. C/D layout: col = lane&15, row = (lane>>4)*4 + reg  [m89/m91]
#pragma unroll
    for (int i = 0; i < 4; i++) {
        int row = rowBase + wr + i * 16 + laneHi * 4;
#pragma unroll
        for (int j = 0; j < 4; j++) {
            int col = colBase + wc + j * 16 + laneLo;
            if (col < D_DIM) {
                float bias = b_alpha[col];
#pragma unroll
                for (int r = 0; r < 4; r++) {
                    float z = acc[i][j][r] + bias;
                    alpha_out[(size_t)(row + r) * D_DIM + col] = sigmoid_f(z);
                }
            } else {
                int c2 = col - D_DIM;
                float bias = b_x[c2];
#pragma unroll
                for (int r = 0; r < 4; r++)
                    wx_out[(size_t)(row + r) * D_DIM + c2] = acc[i][j][r] + bias;
            }
        }
    }
}

// ---------------------------------------------------------------------------
// Sequential scan v7: 3-wave role split (v6 sync structure, validated) with a
// SHORTENED cross-step dependent chain carried in z-space.
//   R6 lesson: wall clock = 2048 x chain latency (~110 cy) -- invariant to
//   blocks/waves/prefetch. Only chain shortening helps.
//   z = C2L*(h + w_t). Per step the critical chain is:
//     e = exp2(z) -> e1 = e+1 -> r = rcp(e1) -> z' = fma(n2u*C2L, r, K)
//   with m = fma(a,h,u), K = fma(m, C2L, C2L*w_{t+1}), h' = fma(n2u, r, m)
//   all issued in the trans-latency shadow. Tile boundary re-enters from
//   h-space (z rebuilt from the new tile's w_0) -> no cross-tile LDS read.
// Loader/storer/barrier/vmcnt structure identical to v6.
// ---------------------------------------------------------------------------
#define TT   32
#define NT   (T_STEPS / TT)   // 64 tiles
#define PF   6                // prefetch distance (tiles)
#define CPB  32               // channels per block
#define SHS  36               // sH row stride (floats), padded

__global__ __launch_bounds__(192)
void scan_kernel(const float* __restrict__ alpha,  // [T][NCH]
                 const float* __restrict__ wx,     // [T][NCH]
                 const float* __restrict__ h0,     // [NCH]
                 float* __restrict__ out,          // [T][NCH]
                 float* __restrict__ hout)         // [T+1][NCH]
{
    __shared__ float sIn[8][2][TT * CPB];   // [buf][0=alpha,1=wx]  64 KB
    __shared__ float sH[2][TT * SHS];       // h ring, padded       9 KB

    const int lane = threadIdx.x & 63;
    const int wid  = threadIdx.x >> 6;
    const int ch0  = blockIdx.x * CPB;

    const float C2L = 2.88539008177792681472f;   // 2*log2(e)

    // loader/storer lane mapping (16 B per lane): 8 lanes per timestep
    const int q8 = lane >> 3;            // timestep sub-offset 0..7
    const int c4 = (lane & 7) * 4;       // channel group

    float h = 0.0f;

    // ---- prologue ----
    if (wid == 1) {
        // stage tiles 0..PF-1 (6 bursts x 8 ops = 48 outstanding)
#pragma unroll
        for (int t = 0; t < PF; ++t)
#pragma unroll
            for (int p = 0; p < TT / 8; ++p) {
                const size_t g = (size_t)(t * TT + p * 8 + q8) * NCH + ch0 + c4;
                glds16(alpha + g, &sIn[t][0][p * 256]);
                glds16(wx    + g, &sIn[t][1][p * 256]);
            }
        // complete G_0; keep G_1..G_5 (40 ops) in flight
        asm volatile("s_waitcnt vmcnt(40)" ::: "memory");
    } else if (wid == 0) {
        if (lane < CPB) h = h0[ch0 + lane];
    } else {
        if (lane < CPB) hout[ch0 + lane] = h0[ch0 + lane];   // row 0
    }
    __builtin_amdgcn_s_barrier();
    __builtin_amdgcn_sched_barrier(0);

    // ---- main loop: one barrier per tile ----
    for (int tile = 0; tile < NT; ++tile) {
        if (wid == 0) {
            // COMPUTE tile from sIn[tile&7]; h trace -> sH[tile&1]
            const float* sA  = &sIn[tile & 7][0][0];
            const float* sW  = &sIn[tile & 7][1][0];
            float* sHc       = &sH[tile & 1][0];
            if (lane < CPB) {
                float zl = (h + sW[lane]) * C2L;   // tile-entry z (h-space)
#pragma unroll
                for (int ts = 0; ts < TT; ++ts) {
                    const float a   = sA[ts * CPB + lane];
                    const float e   = __builtin_amdgcn_exp2f(zl);   // CHAIN
                    const float u   = 1.0f - a;                     // shadow
                    const float n2u = -(u + u);                     // shadow
                    const float m   = fmaf(a, h, u);                // shadow
                    const float r   = __builtin_amdgcn_rcpf(e + 1.0f); // CHAIN
                    if (ts < TT - 1) {
                        const float cwn = sW[(ts + 1) * CPB + lane] * C2L;
                        const float K   = fmaf(m, C2L, cwn);        // shadow
                        zl = fmaf(n2u * C2L, r, K);                 // CHAIN
                    }
                    h = fmaf(n2u, r, m);                            // shadow
                    sHc[ts * SHS + lane] = h;
                }
            }
            asm volatile("s_waitcnt lgkmcnt(0)" ::: "memory");
            __builtin_amdgcn_sched_barrier(0);
        } else if (wid == 1) {
            // LOADER: stage tile+PF, then guarantee tile+1 is resident
            if (tile + PF < NT) {
                const int b  = (tile + PF) & 7;
                const int t0 = (tile + PF) * TT;
#pragma unroll
                for (int p = 0; p < TT / 8; ++p) {
                    const size_t g = (size_t)(t0 + p * 8 + q8) * NCH + ch0 + c4;
                    glds16(alpha + g, &sIn[b][0][p * 256]);
                    glds16(wx    + g, &sIn[b][1][p * 256]);
                }
            }
            // counted drain: complete the burst for tile+1, keep the rest
            {
                const int rem = NT - 1 - tile;
                if (rem >= PF) {
                    asm volatile("s_waitcnt vmcnt(40)" ::: "memory");
                } else if (rem == 5) {
                    asm volatile("s_waitcnt vmcnt(32)" ::: "memory");
                } else if (rem == 4) {
                    asm volatile("s_waitcnt vmcnt(24)" ::: "memory");
                } else if (rem == 3) {
                    asm volatile("s_waitcnt vmcnt(16)" ::: "memory");
                } else if (rem == 2) {
                    asm volatile("s_waitcnt vmcnt(8)" ::: "memory");
                } else if (rem == 1) {
                    asm volatile("s_waitcnt vmcnt(0)" ::: "memory");
                }   // rem == 0: nothing outstanding
            }
            __builtin_amdgcn_sched_barrier(0);
        } else {
            // STORER: flush tile-1's h trace; fused out = h^2 * sigmoid(h)
            if (tile >= 1) {
                const float* sHs = &sH[(tile - 1) & 1][0];
                const int tb = (tile - 1) * TT;
#pragma unroll
                for (int i = 0; i < TT / 8; ++i) {
                    const int tsrow = i * 8 + q8;
                    const float4 hv = *reinterpret_cast<const float4*>(
                        &sHs[tsrow * SHS + c4]);
                    *reinterpret_cast<float4*>(
                        &hout[(size_t)(tb + tsrow + 1) * NCH + ch0 + c4]) = hv;
                    float4 o;
                    o.x = hv.x * hv.x * sigmoid_f(hv.x);
                    o.y = hv.y * hv.y * sigmoid_f(hv.y);
                    o.z = hv.z * hv.z * sigmoid_f(hv.z);
                    o.w = hv.w * hv.w * sigmoid_f(hv.w);
                    *reinterpret_cast<float4*>(
                        &out[(size_t)(tb + tsrow) * NCH + ch0 + c4]) = o;
                }
            }
        }
        __builtin_amdgcn_s_barrier();
        __builtin_amdgcn_sched_barrier(0);
    }

    // ---- epilogue: flush final tile ----
    if (wid == 2) {
        const float* sHs = &sH[(NT - 1) & 1][0];
        const int tb = (NT - 1) * TT;
#pragma unroll
        for (int i = 0; i < TT / 8; ++i) {
            const int tsrow = i * 8 + q8;
            const float4 hv = *reinterpret_cast<const float4*>(
                &sHs[tsrow * SHS + c4]);
            *reinterpret_cast<float4*>(
                &hout[(size_t)(tb + tsrow + 1) * NCH + ch0 + c4]) = hv;
            float4 o;
            o.x = hv.x * hv.x * sigmoid_f(hv.x);
            o.y = hv.y * hv.y * sigmoid_f(hv.y);
            o.z = hv.z * hv.z * sigmoid_f(hv.z);
            o.w = hv.w * hv.w * sigmoid_f(hv.w);
            *reinterpret_cast<float4*>(
                &out[(size_t)(tb + tsrow) * NCH + ch0 + c4]) = o;
        }
    }
}

// ---------------------------------------------------------------------------
extern "C" void kernel_launch(void* const* d_in, const int* in_sizes, int n_in,
                              void* d_out, int out_size, void* d_ws, size_t ws_size,
                              hipStream_t stream) {
    const float* x       = (const float*)d_in[0];  // [T,B,D]
    const float* h0      = (const float*)d_in[1];  // [B,D]
    const float* W_alpha = (const float*)d_in[2];  // [D,D]
    const float* b_alpha = (const float*)d_in[3];  // [D]
    const float* W_x     = (const float*)d_in[4];  // [D,D]
    const float* b       = (const float*)d_in[5];  // [D]

    float* out  = (float*)d_out;                              // [T,B,D]
    float* hout = out + (size_t)T_STEPS * BATCH * D_DIM;      // [T+1,B,D]

    // Workspace layout (~164 MB):
    //   alpha fp32 (64 MB) | wx fp32 (64 MB) | x bf16 (32 MB) | Wc bf16 (4 MB)
    float* ws_alpha = (float*)d_ws;
    float* ws_wx    = ws_alpha + (size_t)M_ROWS * D_DIM;
    unsigned short* ws_x = (unsigned short*)(ws_wx + (size_t)M_ROWS * D_DIM);
    unsigned short* ws_W = ws_x + (size_t)M_ROWS * K_DIM;

    // 1) convert x, W_alpha, W_x to bf16
    {
        int n4 = M_ROWS * K_DIM / 4;
        cvt_bf16_kernel<<<(n4 + 255) / 256, 256, 0, stream>>>(x, ws_x, n4);
    }
    {
        int n4 = D_DIM * K_DIM / 4;
        cvt_bf16_kernel<<<(n4 + 255) / 256, 256, 0, stream>>>(W_alpha, ws_W, n4);
        cvt_bf16_kernel<<<(n4 + 255) / 256, 256, 0, stream>>>(
            W_x, ws_W + (size_t)D_DIM * K_DIM, n4);
    }

    // 2) fused GEMM (N = 2048 covers both projections) + bias + sigmoid epilogue
    {
        dim3 grid(N_COLS / BN, M_ROWS / BM);   // (16, 128)
        gemm_kernel<<<grid, 256, 0, stream>>>(ws_x, ws_W, b_alpha, b,
                                              ws_alpha, ws_wx);
    }

    // 3) sequential scan: 256 blocks x 3 waves (loader / compute / storer)
    scan_kernel<<<NCH / CPB, 192, 0, stream>>>(ws_alpha, ws_wx, h0, out, hout);
}

// Round 9
// 338.090 us; speedup vs baseline: 1.2573x; 1.0282x over previous
//
#include <hip/hip_runtime.h>
#include <hip/hip_bf16.h>
#include <cstdint>
#include <cstddef>

// Problem dims (fixed by the reference)
#define T_STEPS 2048
#define BATCH   8
#define D_DIM   1024
#define M_ROWS  (T_STEPS * BATCH)   // 16384 rows of x
#define N_COLS  (2 * D_DIM)         // 2048: W_alpha rows ++ W_x rows
#define K_DIM   D_DIM               // 1024
#define NCH     (BATCH * D_DIM)     // 8192 independent recurrence channels

// GEMM tiling: 128x128 tile, BK=64 (half the barriers of BK=32)
#define BM 128
#define BN 128
#define BK 64

typedef __bf16 bf16x8 __attribute__((ext_vector_type(8)));
typedef float  f32x4  __attribute__((ext_vector_type(4)));

__device__ __forceinline__ unsigned short f2bf_rne(float f) {
    union { float f; unsigned u; } c; c.f = f;
    unsigned u = c.u;
    u += 0x7fffu + ((u >> 16) & 1u);   // round-to-nearest-even (inputs finite)
    return (unsigned short)(u >> 16);
}

__device__ __forceinline__ float sigmoid_f(float z) {
    return 1.0f / (1.0f + __expf(-z));
}

// async global -> LDS DMA, 16 B per lane; LDS dest = wave-uniform base + lane*16
__device__ __forceinline__ void glds16(const void* gptr, void* lptr) {
    __builtin_amdgcn_global_load_lds(
        (const __attribute__((address_space(1))) unsigned int*)gptr,
        (__attribute__((address_space(3))) unsigned int*)lptr,
        16, 0, 0);
}

// ---------------------------------------------------------------------------
// fp32 -> bf16 convert (vectorized x4)
// ---------------------------------------------------------------------------
__global__ void cvt_bf16_kernel(const float* __restrict__ src,
                                unsigned short* __restrict__ dst, int n4) {
    int i = blockIdx.x * blockDim.x + threadIdx.x;
    if (i >= n4) return;
    float4 v = reinterpret_cast<const float4*>(src)[i];
    ushort4 o;
    o.x = f2bf_rne(v.x); o.y = f2bf_rne(v.y);
    o.z = f2bf_rne(v.z); o.w = f2bf_rne(v.w);
    reinterpret_cast<ushort4*>(dst)[i] = o;
}

// ---------------------------------------------------------------------------
// Fused bf16 MFMA GEMM, BK=64 + block-XOR LDS swizzle.  (validated R8)
//   out[m,n] = sum_k x[m,k] * Wc[n,k]
//   n <  1024 -> alpha_out = sigmoid(acc + b_alpha[n]); else wx_out = acc + b.
// ---------------------------------------------------------------------------
__global__ __launch_bounds__(256, 2)
void gemm_kernel(const unsigned short* __restrict__ A,   // [M][K] bf16 (x)
                 const unsigned short* __restrict__ Bm,  // [N][K] bf16 (W_alpha ++ W_x)
                 const float* __restrict__ b_alpha,      // [D]
                 const float* __restrict__ b_x,          // [D]
                 float* __restrict__ alpha_out,          // [M][D] fp32
                 float* __restrict__ wx_out)             // [M][D] fp32
{
    __shared__ unsigned short sA[BM * BK];   // 16 KB
    __shared__ unsigned short sB[BN * BK];   // 16 KB

    const int tid  = threadIdx.x;
    const int wave = tid >> 6;
    const int lane = tid & 63;

    // XCD swizzle: grid is (16, 128) = 2048 wgs; 2048 % 8 == 0 -> bijective
    const int orig = blockIdx.y * 16 + blockIdx.x;
    const int swz  = (orig & 7) * 256 + (orig >> 3);
    const int rowBase = (swz >> 4) * BM;
    const int colBase = (swz & 15) * BN;

    const int wr = (wave >> 1) * 64;
    const int wc = (wave & 1) * 64;

    const int laneHi = lane >> 4;           // 0..3
    const int laneLo = lane & 15;
    const int rxor   = laneLo & 7;          // row&7 for fragment reads

    // DMA staging: 8 rows per glds16; source col block XOR-swizzled
    const int dRow   = lane >> 3;                    // 0..7
    const int dColSw = ((lane & 7) ^ dRow) * 8;      // shorts

    f32x4 acc[4][4];
#pragma unroll
    for (int i = 0; i < 4; i++)
#pragma unroll
        for (int j = 0; j < 4; j++)
            acc[i][j] = (f32x4)(0.0f);

    for (int k0 = 0; k0 < K_DIM; k0 += BK) {
#pragma unroll
        for (int p = 0; p < 4; ++p) {
            const int seg = wave * 4 + p;   // 8-row segment index, 0..15
            glds16(A + (size_t)(rowBase + seg * 8 + dRow) * K_DIM + k0 + dColSw,
                   &sA[seg * 512]);
            glds16(Bm + (size_t)(colBase + seg * 8 + dRow) * K_DIM + k0 + dColSw,
                   &sB[seg * 512]);
        }
        __syncthreads();   // drains vmcnt(0) -> LDS tiles ready

#pragma unroll
        for (int kk = 0; kk < 2; ++kk) {
            bf16x8 af[4], bfr[4];
#pragma unroll
            for (int i = 0; i < 4; i++) {
                const int row = wr + i * 16 + laneLo;
                af[i] = *reinterpret_cast<const bf16x8*>(
                    &sA[row * BK + (((kk << 2) + laneHi) ^ rxor) * 8]);
            }
#pragma unroll
            for (int j = 0; j < 4; j++) {
                const int row = wc + j * 16 + laneLo;
                bfr[j] = *reinterpret_cast<const bf16x8*>(
                    &sB[row * BK + (((kk << 2) + laneHi) ^ rxor) * 8]);
            }
#pragma unroll
            for (int i = 0; i < 4; i++)
#pragma unroll
                for (int j = 0; j < 4; j++)
                    acc[i][j] = __builtin_amdgcn_mfma_f32_16x16x32_bf16(
                        af[i], bfr[j], acc[i][j], 0, 0, 0);
        }
        __syncthreads();   // all reads done; LDS free for next k-step
    }

    // Epilogue. C/D layout: col = lane&15, row = (lane>>4)*4 + reg  [m89/m91]
#pragma unroll
    for (int i = 0; i < 4; i++) {
        int row = rowBase + wr + i * 16 + laneHi * 4;
#pragma unroll
        for (int j = 0; j < 4; j++) {
            int col = colBase + wc + j * 16 + laneLo;
            if (col < D_DIM) {
                float bias = b_alpha[col];
#pragma unroll
                for (int r = 0; r < 4; r++) {
                    float z = acc[i][j][r] + bias;
                    alpha_out[(size_t)(row + r) * D_DIM + col] = sigmoid_f(z);
                }
            } else {
                int c2 = col - D_DIM;
                float bias = b_x[c2];
#pragma unroll
                for (int r = 0; r < 4; r++)
                    wx_out[(size_t)(row + r) * D_DIM + c2] = acc[i][j][r] + bias;
            }
        }
    }
}

// ---------------------------------------------------------------------------
// Sequential scan v8: 3-wave role split + REGISTER-PRELOADED compute tile.
//   R8 diagnosis: every scan variant sat at ~110-130 cy/step == the ~120 cy
//   single-outstanding ds_read_b32 latency. The compiler sinks each step's
//   LDS read to just-before-use, putting the LDS round-trip ON the serial
//   chain. The arithmetic refactors (R1/R7) never touched the real path.
//   Fix: compute wave preloads the whole tile into registers as an
//   independent ds_read burst (aR[32]/wR[32], static indices -> VGPRs),
//   pinned above the chain with sched_barrier(0). LDS latency paid once per
//   tile (in-order lgkm FIFO); the 32-step chain then runs pure-VALU:
//     e = exp2(z) -> r = rcp(e+1) -> z' = fma   (z-space, trans-limited)
//   wave1 LOADER / wave2 STORER / barrier / counted-vmcnt: identical to v7
//   (validated R8; no sync-structure change).
// ---------------------------------------------------------------------------
#define TT   32
#define NT   (T_STEPS / TT)   // 64 tiles
#define PF   6                // prefetch distance (tiles)
#define CPB  32               // channels per block
#define SHS  36               // sH row stride (floats), padded

__global__ __launch_bounds__(192)
void scan_kernel(const float* __restrict__ alpha,  // [T][NCH]
                 const float* __restrict__ wx,     // [T][NCH]
                 const float* __restrict__ h0,     // [NCH]
                 float* __restrict__ out,          // [T][NCH]
                 float* __restrict__ hout)         // [T+1][NCH]
{
    __shared__ float sIn[8][2][TT * CPB];   // [buf][0=alpha,1=wx]  64 KB
    __shared__ float sH[2][TT * SHS];       // h ring, padded       9 KB

    const int lane = threadIdx.x & 63;
    const int wid  = threadIdx.x >> 6;
    const int ch0  = blockIdx.x * CPB;

    const float C2L = 2.88539008177792681472f;   // 2*log2(e)

    // loader/storer lane mapping (16 B per lane): 8 lanes per timestep
    const int q8 = lane >> 3;            // timestep sub-offset 0..7
    const int c4 = (lane & 7) * 4;       // channel group

    float h = 0.0f;

    // ---- prologue ----
    if (wid == 1) {
        // stage tiles 0..PF-1 (6 bursts x 8 ops = 48 outstanding)
#pragma unroll
        for (int t = 0; t < PF; ++t)
#pragma unroll
            for (int p = 0; p < TT / 8; ++p) {
                const size_t g = (size_t)(t * TT + p * 8 + q8) * NCH + ch0 + c4;
                glds16(alpha + g, &sIn[t][0][p * 256]);
                glds16(wx    + g, &sIn[t][1][p * 256]);
            }
        // complete G_0; keep G_1..G_5 (40 ops) in flight
        asm volatile("s_waitcnt vmcnt(40)" ::: "memory");
    } else if (wid == 0) {
        if (lane < CPB) h = h0[ch0 + lane];
    } else {
        if (lane < CPB) hout[ch0 + lane] = h0[ch0 + lane];   // row 0
    }
    __builtin_amdgcn_s_barrier();
    __builtin_amdgcn_sched_barrier(0);

    // ---- main loop: one barrier per tile ----
    for (int tile = 0; tile < NT; ++tile) {
        if (wid == 0) {
            // COMPUTE tile from sIn[tile&7]; h trace -> sH[tile&1]
            const float* sA  = &sIn[tile & 7][0][0];
            const float* sW  = &sIn[tile & 7][1][0];
            float* sHc       = &sH[tile & 1][0];
            if (lane < CPB) {
                // (1) independent register burst: 64 ds_read_b32, in-order
                //     lgkm FIFO -> first use waits one latency, rest stream.
                float aR[TT], wR[TT];
#pragma unroll
                for (int ts = 0; ts < TT; ++ts) {
                    aR[ts] = sA[ts * CPB + lane];
                    wR[ts] = sW[ts * CPB + lane];
                }
                __builtin_amdgcn_sched_barrier(0);   // pin burst above chain
                // (2) pure-VALU serial chain (z-space)
                float zl = fmaf(h, C2L, wR[0] * C2L);
#pragma unroll
                for (int ts = 0; ts < TT; ++ts) {
                    const float a   = aR[ts];
                    const float e   = __builtin_amdgcn_exp2f(zl);      // CHAIN
                    const float u   = 1.0f - a;                        // shadow
                    const float n2u = -(u + u);                        // shadow
                    const float m   = fmaf(a, h, u);                   // shadow
                    const float r   = __builtin_amdgcn_rcpf(e + 1.0f); // CHAIN
                    if (ts < TT - 1) {
                        const float K = fmaf(m, C2L, wR[ts + 1] * C2L); // shadow
                        zl = fmaf(n2u * C2L, r, K);                    // CHAIN
                    }
                    h = fmaf(n2u, r, m);                               // shadow
                    sHc[ts * SHS + lane] = h;
                }
            }
            asm volatile("s_waitcnt lgkmcnt(0)" ::: "memory");
            __builtin_amdgcn_sched_barrier(0);
        } else if (wid == 1) {
            // LOADER: stage tile+PF, then guarantee tile+1 is resident
            if (tile + PF < NT) {
                const int b  = (tile + PF) & 7;
                const int t0 = (tile + PF) * TT;
#pragma unroll
                for (int p = 0; p < TT / 8; ++p) {
                    const size_t g = (size_t)(t0 + p * 8 + q8) * NCH + ch0 + c4;
                    glds16(alpha + g, &sIn[b][0][p * 256]);
                    glds16(wx    + g, &sIn[b][1][p * 256]);
                }
            }
            // counted drain: complete the burst for tile+1, keep the rest
            {
                const int rem = NT - 1 - tile;
                if (rem >= PF) {
                    asm volatile("s_waitcnt vmcnt(40)" ::: "memory");
                } else if (rem == 5) {
                    asm volatile("s_waitcnt vmcnt(32)" ::: "memory");
                } else if (rem == 4) {
                    asm volatile("s_waitcnt vmcnt(24)" ::: "memory");
                } else if (rem == 3) {
                    asm volatile("s_waitcnt vmcnt(16)" ::: "memory");
                } else if (rem == 2) {
                    asm volatile("s_waitcnt vmcnt(8)" ::: "memory");
                } else if (rem == 1) {
                    asm volatile("s_waitcnt vmcnt(0)" ::: "memory");
                }   // rem == 0: nothing outstanding
            }
            __builtin_amdgcn_sched_barrier(0);
        } else {
            // STORER: flush tile-1's h trace; fused out = h^2 * sigmoid(h)
            if (tile >= 1) {
                const float* sHs = &sH[(tile - 1) & 1][0];
                const int tb = (tile - 1) * TT;
#pragma unroll
                for (int i = 0; i < TT / 8; ++i) {
                    const int tsrow = i * 8 + q8;
                    const float4 hv = *reinterpret_cast<const float4*>(
                        &sHs[tsrow * SHS + c4]);
                    *reinterpret_cast<float4*>(
                        &hout[(size_t)(tb + tsrow + 1) * NCH + ch0 + c4]) = hv;
                    float4 o;
                    o.x = hv.x * hv.x * sigmoid_f(hv.x);
                    o.y = hv.y * hv.y * sigmoid_f(hv.y);
                    o.z = hv.z * hv.z * sigmoid_f(hv.z);
                    o.w = hv.w * hv.w * sigmoid_f(hv.w);
                    *reinterpret_cast<float4*>(
                        &out[(size_t)(tb + tsrow) * NCH + ch0 + c4]) = o;
                }
            }
        }
        __builtin_amdgcn_s_barrier();
        __builtin_amdgcn_sched_barrier(0);
    }

    // ---- epilogue: flush final tile ----
    if (wid == 2) {
        const float* sHs = &sH[(NT - 1) & 1][0];
        const int tb = (NT - 1) * TT;
#pragma unroll
        for (int i = 0; i < TT / 8; ++i) {
            const int tsrow = i * 8 + q8;
            const float4 hv = *reinterpret_cast<const float4*>(
                &sHs[tsrow * SHS + c4]);
            *reinterpret_cast<float4*>(
                &hout[(size_t)(tb + tsrow + 1) * NCH + ch0 + c4]) = hv;
            float4 o;
            o.x = hv.x * hv.x * sigmoid_f(hv.x);
            o.y = hv.y * hv.y * sigmoid_f(hv.y);
            o.z = hv.z * hv.z * sigmoid_f(hv.z);
            o.w = hv.w * hv.w * sigmoid_f(hv.w);
            *reinterpret_cast<float4*>(
                &out[(size_t)(tb + tsrow) * NCH + ch0 + c4]) = o;
        }
    }
}

// ---------------------------------------------------------------------------
extern "C" void kernel_launch(void* const* d_in, const int* in_sizes, int n_in,
                              void* d_out, int out_size, void* d_ws, size_t ws_size,
                              hipStream_t stream) {
    const float* x       = (const float*)d_in[0];  // [T,B,D]
    const float* h0      = (const float*)d_in[1];  // [B,D]
    const float* W_alpha = (const float*)d_in[2];  // [D,D]
    const float* b_alpha = (const float*)d_in[3];  // [D]
    const float* W_x     = (const float*)d_in[4];  // [D,D]
    const float* b       = (const float*)d_in[5];  // [D]

    float* out  = (float*)d_out;                              // [T,B,D]
    float* hout = out + (size_t)T_STEPS * BATCH * D_DIM;      // [T+1,B,D]

    // Workspace layout (~164 MB):
    //   alpha fp32 (64 MB) | wx fp32 (64 MB) | x bf16 (32 MB) | Wc bf16 (4 MB)
    float* ws_alpha = (float*)d_ws;
    float* ws_wx    = ws_alpha + (size_t)M_ROWS * D_DIM;
    unsigned short* ws_x = (unsigned short*)(ws_wx + (size_t)M_ROWS * D_DIM);
    unsigned short* ws_W = ws_x + (size_t)M_ROWS * K_DIM;

    // 1) convert x, W_alpha, W_x to bf16
    {
        int n4 = M_ROWS * K_DIM / 4;
        cvt_bf16_kernel<<<(n4 + 255) / 256, 256, 0, stream>>>(x, ws_x, n4);
    }
    {
        int n4 = D_DIM * K_DIM / 4;
        cvt_bf16_kernel<<<(n4 + 255) / 256, 256, 0, stream>>>(W_alpha, ws_W, n4);
        cvt_bf16_kernel<<<(n4 + 255) / 256, 256, 0, stream>>>(
            W_x, ws_W + (size_t)D_DIM * K_DIM, n4);
    }

    // 2) fused GEMM (N = 2048 covers both projections) + bias + sigmoid epilogue
    {
        dim3 grid(N_COLS / BN, M_ROWS / BM);   // (16, 128)
        gemm_kernel<<<grid, 256, 0, stream>>>(ws_x, ws_W, b_alpha, b,
                                              ws_alpha, ws_wx);
    }

    // 3) sequential scan: 256 blocks x 3 waves (loader / compute / storer)
    scan_kernel<<<NCH / CPB, 192, 0, stream>>>(ws_alpha, ws_wx, h0, out, hout);
}